// Round 6
// baseline (50.246 us; speedup 1.0000x reference)
//
#include <hip/hip_runtime.h>
#include <stdint.h>

// 4-point Hermite resampler — barrier-free wave-private LDS pipeline, v3.
// Changes vs round 5:
//  * lane-interleaved sample map (j = jw + k*64 + lane): gather taps stride
//    ~1.088 floats across lanes -> ~2-way LDS bank aliasing (free) instead of
//    the 8-way stride-4 pattern of the consecutive-float4 map.
//  * x / y0 computed on device from the host-passed fp64 `scaling` (bitwise
//    identical to numpy's arange*scaling + floor) -> x/idx arrays never read.
//  * main kernel covers only FULL 1024-sample tiles (no masks -> vmem counts
//    uniform, counted-vmcnt provably correct); 820-sample tail = tiny kernel.
//  * WFL 288 (need 283): 1.7% over-stage. 4 bufs x 4 waves x 288 f = 18 KB.
//  * store-aware counted vmcnt, 2 loads + 4 stores per iter:
//    prologue 6/10/14, steady 18 (keeps 3 windows + 3 store sets in flight).

#define NW   4
#define OPW  256
#define TILE (NW * OPW)    // 1024 outputs per block
#define WFL  288           // staged floats per window
#define CPB  16            // channels per block (grid.y = 2)
#define NCH  32

typedef const __attribute__((address_space(1))) uint32_t* gas_t;
typedef __attribute__((address_space(3))) uint32_t* las_t;

__device__ __forceinline__ void stage_win(const float* g, float* l, int lane) {
    // lane i: 16B from g+16i -> LDS l + 16i (wave-uniform LDS base)
    __builtin_amdgcn_global_load_lds((gas_t)g, (las_t)l, 16, 0, 0);
    if (lane < 8)   // floats [256, 288)
        __builtin_amdgcn_global_load_lds((gas_t)(g + 256), (las_t)(l + 256), 16, 0, 0);
}

template<bool INTERIOR>
__device__ __forceinline__ void run(
    const float* __restrict__ gb, float* __restrict__ op, size_t chstride,
    int out_bs, float* b0, float* b1, float* b2, float* b3, int lane,
    const int* rr, const int* am1, const int* a1, const int* a2,
    const float* xw)
{
    stage_win(gb + 0 * chstride, b0, lane);
    stage_win(gb + 1 * chstride, b1, lane);
    stage_win(gb + 2 * chstride, b2, lane);

#define HBODY(S, CUR, NXT, CNT)                                               \
  {                                                                           \
    const int sn = ((S) + 3 < CPB) ? (S) + 3 : CPB - 1;  /* dead restage */   \
    stage_win(gb + (size_t)sn * chstride, NXT, lane);                         \
    asm volatile("s_waitcnt vmcnt(" #CNT ")" ::: "memory");                   \
    __builtin_amdgcn_sched_barrier(0);                                        \
    _Pragma("unroll")                                                         \
    for (int k = 0; k < 4; ++k) {                                             \
      float ym1, y0f, y1f, y2f;                                               \
      if (INTERIOR) {                                                         \
        const float* p = (CUR) + rr[k];                                       \
        ym1 = p[-1]; y0f = p[0]; y1f = p[1]; y2f = p[2];                      \
      } else {                                                                \
        ym1 = (CUR)[am1[k]]; y0f = (CUR)[rr[k]];                              \
        y1f = (CUR)[a1[k]];  y2f = (CUR)[a2[k]];                              \
      }                                                                       \
      const float c1 = 0.5f * (y1f - ym1);                                    \
      const float c2 = ym1 - 2.5f * y0f + 2.0f * y1f - 0.5f * y2f;            \
      const float c3 = 0.5f * (y2f - ym1) + 1.5f * (y0f - y1f);               \
      const float xx = xw[k];                                                 \
      const float o  = ((c3 * xx + c2) * xx + c1) * xx + y0f;                 \
      __builtin_nontemporal_store(o, op + (size_t)(S) * (size_t)out_bs + k * 64); \
    }                                                                         \
  }

    HBODY(0, b0, b3, 6)
    HBODY(1, b1, b0, 10)
    HBODY(2, b2, b1, 14)
    HBODY(3, b3, b2, 18)
    for (int ss = 4; ss < CPB; ss += 4) {
        HBODY(ss + 0, b0, b3, 18)
        HBODY(ss + 1, b1, b0, 18)
        HBODY(ss + 2, b2, b1, 18)
        HBODY(ss + 3, b3, b2, 18)
    }
#undef HBODY
}

__global__ __launch_bounds__(256) void hermite_main_kernel(
    const float* __restrict__ y,       // [32, in_bs]
    float* __restrict__ out,           // [32, out_bs]
    int out_bs, int in_bs, double scaling)
{
    __shared__ float sbuf[NW][4][WFL];   // 18 KB -> 8 blocks/CU
    const int t    = threadIdx.x;
    const int w    = t >> 6;
    const int lane = t & 63;
    const int jw   = blockIdx.x * TILE + w * OPW;   // all samples valid here
    const int ch0  = blockIdx.y * CPB;

    // wave-uniform window base from computed y0(jw)
    const int y0w = (int)__builtin_floor((double)jw * scaling);
    int src = (y0w - 1) & ~3;
    src = max(src, 0);
    src = min(src, in_bs - WFL);

    // per-lane x and tap offsets (bitwise-identical to numpy's fp64 path),
    // loop-invariant across channels
    float xw[4]; int rr[4], am1[4], a1[4], a2[4];
    #pragma unroll
    for (int k = 0; k < 4; ++k) {
        const int    jk = jw + k * 64 + lane;
        const double xf = (double)jk * scaling;
        const double fl = __builtin_floor(xf);
        const int    y0 = (int)fl;
        xw[k]  = (float)fmin(fmax(xf - fl, 0.0), 1.0);
        rr[k]  = y0 - src;
        am1[k] = max(y0 - 1, 0) - src;
        a1[k]  = min(y0 + 1, in_bs - 1) - src;
        a2[k]  = min(y0 + 2, in_bs - 1) - src;
    }

    const float* gb = y + (size_t)ch0 * (size_t)in_bs + src + 4 * lane;
    float*       op = out + (size_t)ch0 * (size_t)out_bs + jw + lane;
    float* b0 = &sbuf[w][0][0];
    float* b1 = &sbuf[w][1][0];
    float* b2 = &sbuf[w][2][0];
    float* b3 = &sbuf[w][3][0];

    // only block (0, *) wave 0 can hit the y0-1 clamp; end clamps never bind
    // in full tiles (max y0+2 << in_bs-1).
    if (y0w >= 1)
        run<true >(gb, op, (size_t)in_bs, out_bs, b0, b1, b2, b3, lane,
                   rr, am1, a1, a2, xw);
    else
        run<false>(gb, op, (size_t)in_bs, out_bs, b0, b1, b2, b3, lane,
                   rr, am1, a1, a2, xw);
}

__global__ __launch_bounds__(256) void hermite_tail_kernel(
    const float* __restrict__ y, float* __restrict__ out,
    int out_bs, int in_bs, double scaling, int j0, int n)
{
    const int idx = blockIdx.x * 256 + threadIdx.x;
    if (idx >= n * NCH) return;
    const int jr = idx % n;
    const int ch = idx / n;
    const int j  = j0 + jr;

    const double xf = (double)j * scaling;
    const double fl = __builtin_floor(xf);
    const int    y0 = (int)fl;
    double xd = fmin(fmax(xf - fl, 0.0), 1.0);
    if (j == out_bs - 1) xd = __builtin_rint(xd);   // np: x[-1] = round(x[-1])
    const float xx = (float)xd;

    const float* yc = y + (size_t)ch * (size_t)in_bs;
    const float ym1 = yc[max(y0 - 1, 0)];
    const float y0f = yc[y0];
    const float y1f = yc[min(y0 + 1, in_bs - 1)];
    const float y2f = yc[min(y0 + 2, in_bs - 1)];
    const float c1 = 0.5f * (y1f - ym1);
    const float c2 = ym1 - 2.5f * y0f + 2.0f * y1f - 0.5f * y2f;
    const float c3 = 0.5f * (y2f - ym1) + 1.5f * (y0f - y1f);
    out[(size_t)ch * (size_t)out_bs + j] = ((c3 * xx + c2) * xx + c1) * xx + y0f;
}

extern "C" void kernel_launch(void* const* d_in, const int* in_sizes, int n_in,
                              void* d_out, int out_size, void* d_ws, size_t ws_size,
                              hipStream_t stream)
{
    const float* y   = (const float*)d_in[0];
    float*       out = (float*)d_out;

    const int out_bs = in_sizes[1];           // 963380
    const int n_ch   = out_size / out_bs;     // 32
    const int in_bs  = in_sizes[0] / n_ch;    // 1048576

    // identical IEEE fp64 value to numpy's (in_bs-1)/(out_bs-1) + 1e-12
    const double scaling = (double)(in_bs - 1) / (double)(out_bs - 1) + 1e-12;

    const int full   = out_bs / TILE;         // 940 full tiles
    const int j_tail = full * TILE;           // 962560
    const int n_tail = out_bs - j_tail;       // 820

    dim3 grid(full, n_ch / CPB, 1);           // (940, 2)
    hermite_main_kernel<<<grid, 256, 0, stream>>>(y, out, out_bs, in_bs, scaling);

    const int tail_threads = n_tail * n_ch;   // 26240
    hermite_tail_kernel<<<(tail_threads + 255) / 256, 256, 0, stream>>>(
        y, out, out_bs, in_bs, scaling, j_tail, n_tail);
}

// Round 7
// 46.150 us; speedup vs baseline: 1.0888x; 1.0888x over previous
//
#include <hip/hip_runtime.h>
#include <stdint.h>

// 4-point Hermite resampler — barrier-free wave-private LDS pipeline, v4.
// = round-5 structure (4 consecutive outputs/thread, dwordx4 NT stores,
//   depth-3 channel pipeline, store-aware counted vmcnt 6/7/8/9)
// + round-6's device-computed x / y0 from the fp64 scaling (no x/idx fetch;
//   bitwise-identical to numpy), full-tile main kernel + tiny tail kernel
// + CPB=8 with grid.y=4: 3760 blocks (14.7/CU) for load balance / streams.
// LDS: 4 waves x 4 buffers x 288 floats = 18 KB -> 8 blocks/CU.

#define NW   4
#define OPW  256
#define TILE (NW * OPW)    // 1024 outputs per block
#define WFL  288           // staged floats per window (need <=283)
#define CPB  8             // channels per block (grid.y = 4)
#define NCH  32

typedef float vf4 __attribute__((ext_vector_type(4)));

typedef const __attribute__((address_space(1))) uint32_t* gas_t;
typedef __attribute__((address_space(3))) uint32_t* las_t;

__device__ __forceinline__ void stage_win(const float* g, float* l, int lane) {
    // lane i: 16B from g+16i -> LDS l+16i (wave-uniform LDS base, linear)
    __builtin_amdgcn_global_load_lds((gas_t)g, (las_t)l, 16, 0, 0);
    if (lane < 8)   // floats [256, 288)
        __builtin_amdgcn_global_load_lds((gas_t)(g + 256), (las_t)(l + 256), 16, 0, 0);
}

template<bool INTERIOR>
__device__ __forceinline__ void run(
    const float* __restrict__ gb, float* __restrict__ op, size_t chstride,
    int out_bs, float* b0, float* b1, float* b2, float* b3, int lane,
    const int* rr, const int* am1, const int* a1, const int* a2,
    const float* xw)
{
    stage_win(gb + 0 * chstride, b0, lane);
    stage_win(gb + 1 * chstride, b1, lane);
    stage_win(gb + 2 * chstride, b2, lane);

#define HBODY(S, CUR, NXT, CNT)                                               \
  {                                                                           \
    const int sn = ((S) + 3 < CPB) ? (S) + 3 : CPB - 1;  /* dead restage */   \
    stage_win(gb + (size_t)sn * chstride, NXT, lane);                         \
    asm volatile("s_waitcnt vmcnt(" #CNT ")" ::: "memory");                   \
    __builtin_amdgcn_sched_barrier(0);                                        \
    vf4 o;                                                                    \
    _Pragma("unroll")                                                         \
    for (int k = 0; k < 4; ++k) {                                             \
      float ym1, y0f, y1f, y2f;                                               \
      if (INTERIOR) {                                                         \
        const float* p = (CUR) + rr[k];                                       \
        ym1 = p[-1]; y0f = p[0]; y1f = p[1]; y2f = p[2];                      \
      } else {                                                                \
        ym1 = (CUR)[am1[k]]; y0f = (CUR)[rr[k]];                              \
        y1f = (CUR)[a1[k]];  y2f = (CUR)[a2[k]];                              \
      }                                                                       \
      const float c1 = 0.5f * (y1f - ym1);                                    \
      const float c2 = ym1 - 2.5f * y0f + 2.0f * y1f - 0.5f * y2f;            \
      const float c3 = 0.5f * (y2f - ym1) + 1.5f * (y0f - y1f);               \
      const float xx = xw[k];                                                 \
      o[k] = ((c3 * xx + c2) * xx + c1) * xx + y0f;                           \
    }                                                                         \
    __builtin_nontemporal_store(o, (vf4*)(op + (size_t)(S) * (size_t)out_bs)); \
  }

    HBODY(0, b0, b3, 6)
    HBODY(1, b1, b0, 7)
    HBODY(2, b2, b1, 8)
    HBODY(3, b3, b2, 9)
    for (int ss = 4; ss < CPB; ss += 4) {
        HBODY(ss + 0, b0, b3, 9)
        HBODY(ss + 1, b1, b0, 9)
        HBODY(ss + 2, b2, b1, 9)
        HBODY(ss + 3, b3, b2, 9)
    }
#undef HBODY
}

__global__ __launch_bounds__(256) void hermite_main_kernel(
    const float* __restrict__ y,       // [32, in_bs]
    float* __restrict__ out,           // [32, out_bs]
    int out_bs, int in_bs, double scaling)
{
    __shared__ float sbuf[NW][4][WFL];   // 18 KB -> 8 blocks/CU
    const int t    = threadIdx.x;
    const int w    = t >> 6;
    const int lane = t & 63;
    const int jw   = blockIdx.x * TILE + w * OPW;   // full tiles only
    const int j    = jw + 4 * lane;                 // thread's 4 outputs
    const int ch0  = blockIdx.y * CPB;

    // wave-uniform window base from computed y0(jw), 16B-aligned
    const int y0w = (int)__builtin_floor((double)jw * scaling);
    int src = (y0w - 1) & ~3;
    src = max(src, 0);
    src = min(src, in_bs - WFL);

    // per-thread x and tap offsets (bitwise-identical to numpy fp64 path),
    // loop-invariant across channels
    float xw[4]; int rr[4], am1[4], a1[4], a2[4];
    #pragma unroll
    for (int k = 0; k < 4; ++k) {
        const int    jk = j + k;
        const double xf = (double)jk * scaling;
        const double fl = __builtin_floor(xf);
        const int    y0 = (int)fl;
        xw[k]  = (float)fmin(fmax(xf - fl, 0.0), 1.0);
        rr[k]  = y0 - src;
        am1[k] = max(y0 - 1, 0) - src;
        a1[k]  = min(y0 + 1, in_bs - 1) - src;
        a2[k]  = min(y0 + 2, in_bs - 1) - src;
    }

    const float* gb = y + (size_t)ch0 * (size_t)in_bs + src + 4 * lane;
    float*       op = out + (size_t)ch0 * (size_t)out_bs + j;
    float* b0 = &sbuf[w][0][0];
    float* b1 = &sbuf[w][1][0];
    float* b2 = &sbuf[w][2][0];
    float* b3 = &sbuf[w][3][0];

    // only tile 0 / wave 0 can hit the y0-1 clamp; end clamps never bind in
    // full tiles (max y0+2 << in_bs-1)
    const bool interior = (src >= 4) && (src + WFL + 4 <= in_bs);
    if (interior)
        run<true >(gb, op, (size_t)in_bs, out_bs, b0, b1, b2, b3, lane,
                   rr, am1, a1, a2, xw);
    else
        run<false>(gb, op, (size_t)in_bs, out_bs, b0, b1, b2, b3, lane,
                   rr, am1, a1, a2, xw);
}

__global__ __launch_bounds__(256) void hermite_tail_kernel(
    const float* __restrict__ y, float* __restrict__ out,
    int out_bs, int in_bs, double scaling, int j0, int n)
{
    const int idx = blockIdx.x * 256 + threadIdx.x;
    if (idx >= n * NCH) return;
    const int jr = idx % n;
    const int ch = idx / n;
    const int j  = j0 + jr;

    const double xf = (double)j * scaling;
    const double fl = __builtin_floor(xf);
    const int    y0 = (int)fl;
    double xd = fmin(fmax(xf - fl, 0.0), 1.0);
    if (j == out_bs - 1) xd = __builtin_rint(xd);   // np: x[-1] = round(x[-1])
    const float xx = (float)xd;

    const float* yc = y + (size_t)ch * (size_t)in_bs;
    const float ym1 = yc[max(y0 - 1, 0)];
    const float y0f = yc[y0];
    const float y1f = yc[min(y0 + 1, in_bs - 1)];
    const float y2f = yc[min(y0 + 2, in_bs - 1)];
    const float c1 = 0.5f * (y1f - ym1);
    const float c2 = ym1 - 2.5f * y0f + 2.0f * y1f - 0.5f * y2f;
    const float c3 = 0.5f * (y2f - ym1) + 1.5f * (y0f - y1f);
    out[(size_t)ch * (size_t)out_bs + j] = ((c3 * xx + c2) * xx + c1) * xx + y0f;
}

extern "C" void kernel_launch(void* const* d_in, const int* in_sizes, int n_in,
                              void* d_out, int out_size, void* d_ws, size_t ws_size,
                              hipStream_t stream)
{
    const float* y   = (const float*)d_in[0];
    float*       out = (float*)d_out;

    const int out_bs = in_sizes[1];           // 963380
    const int n_ch   = out_size / out_bs;     // 32
    const int in_bs  = in_sizes[0] / n_ch;    // 1048576

    // identical IEEE fp64 value to numpy's (in_bs-1)/(out_bs-1) + 1e-12
    const double scaling = (double)(in_bs - 1) / (double)(out_bs - 1) + 1e-12;

    const int full   = out_bs / TILE;         // 940 full tiles
    const int j_tail = full * TILE;           // 962560
    const int n_tail = out_bs - j_tail;       // 820

    dim3 grid(full, n_ch / CPB, 1);           // (940, 4)
    hermite_main_kernel<<<grid, 256, 0, stream>>>(y, out, out_bs, in_bs, scaling);

    const int tail_threads = n_tail * n_ch;   // 26240
    hermite_tail_kernel<<<(tail_threads + 255) / 256, 256, 0, stream>>>(
        y, out, out_bs, in_bs, scaling, j_tail, n_tail);
}